// Round 1
// baseline (125.447 us; speedup 1.0000x reference)
//
#include <hip/hip_runtime.h>

#define NB 4096
#define SS 102
#define HID 8      // HIDDEN
#define NH 2       // HEADS
#define HD 4       // HEAD_DIM

// LDS layout:
//  sRaw : [3][102][8] raw query/key/value rows (first 816 floats reused as
//         head-combined attention output before the wo projection)
//  sP   : [3][2][102][4] rotated-q / rotated-k / v in head-split layout
//  sW   : [4][64] wq, wk, wv, wo
__global__ __launch_bounds__(256, 4) void mha_fused_kernel(
    const float* __restrict__ query, const float* __restrict__ key,
    const float* __restrict__ value, const float* __restrict__ wq,
    const float* __restrict__ wk, const float* __restrict__ wv,
    const float* __restrict__ wo, float* __restrict__ out)
{
    __shared__ float sRaw[3 * SS * HID];        // 2448 floats
    __shared__ float sP[3 * NH * SS * HD];      // 2448 floats
    __shared__ float sW[4 * 64];                // 256 floats

    const int t = threadIdx.x;
    const int b = blockIdx.x;

    // ---- load weights (one float per thread) ----
    if (t < 64)        sW[t]       = wq[t];
    else if (t < 128)  sW[t]       = wk[t - 64];
    else if (t < 192)  sW[t]       = wv[t - 128];
    else               sW[t]       = wo[t - 192];

    // ---- stage raw inputs, coalesced float4 (204 float4 per tensor) ----
    {
        const float4* q4 = (const float4*)(query + (size_t)b * (SS * HID));
        const float4* k4 = (const float4*)(key   + (size_t)b * (SS * HID));
        const float4* v4 = (const float4*)(value + (size_t)b * (SS * HID));
        float4* sRaw4 = (float4*)sRaw;
        if (t < 204) {
            sRaw4[t]           = q4[t];
            sRaw4[204 + t]     = k4[t];
            sRaw4[408 + t]     = v4[t];
        }
    }
    __syncthreads();

    // ---- q/k projection + fused rotary ----
    // 408 rotary pairs per tensor (q: p in [0,408), k: p in [408,816))
    // rotary (matching the reference's broadcast quirk):
    //   w = sin(s) for head 0, cos(s) for head 1  (inv_freq == 1.0)
    //   out[d_even] = (x_even - x_odd) * w ; out[d_odd] = (x_odd + x_even) * w
    for (int p = t; p < 816; p += 256) {
        const int tensor = p / 408;          // 0 = q, 1 = k
        const int pp = p % 408;
        const int s  = pp >> 2;              // seq position 0..101
        const int pr = pp & 3;               // pair index 0..3
        const int i0 = pr * 2, i1 = i0 + 1;  // projected channel indices
        const float* raw = sRaw + tensor * (SS * HID) + s * HID;
        const float* w   = sW + tensor * 64;
        float x0 = 0.f, x1 = 0.f;
#pragma unroll
        for (int j = 0; j < 8; ++j) {
            x0 += raw[j] * w[i0 * 8 + j];
            x1 += raw[j] * w[i1 * 8 + j];
        }
        const int h = i0 >> 2;               // head
        const float wr = (h == 0) ? sinf((float)s) : cosf((float)s);
        const float r0 = (x0 - x1) * wr;
        const float r1 = (x1 + x0) * wr;
        const int d0 = i0 & 3;               // dim within head (even)
        float* dst = sP + tensor * (NH * SS * HD) + h * (SS * HD) + s * HD + d0;
        dst[0] = r0;
        dst[1] = r1;
    }
    // ---- v projection (no rotary), 816 elements ----
    for (int e = t; e < 816; e += 256) {
        const int s = e >> 3, i = e & 7;
        const float* raw = sRaw + 2 * (SS * HID) + s * HID;
        const float* w   = sW + 2 * 64 + i * 8;
        float x = 0.f;
#pragma unroll
        for (int j = 0; j < 8; ++j) x += raw[j] * w[j];
        const int h = i >> 2, d = i & 3;
        sP[2 * (NH * SS * HD) + h * (SS * HD) + s * HD + d] = x;
    }
    __syncthreads();

    // ---- attention: one thread per (head, q-row); 204 active threads ----
    float acc0 = 0.f, acc1 = 0.f, acc2 = 0.f, acc3 = 0.f, l = 0.f;
    int h = 0, qr = 0;
    if (t < 204) {
        h = t / SS;
        qr = t - h * SS;
        const float4 qv = *(const float4*)(sP + h * (SS * HD) + qr * HD);
        // fold the 1/sqrt(HEAD_DIM)=0.5 score scale into q
        const float q0 = qv.x * 0.5f, q1 = qv.y * 0.5f,
                    q2 = qv.z * 0.5f, q3 = qv.w * 0.5f;
        const float4* K4 = (const float4*)(sP + 1 * (NH * SS * HD) + h * (SS * HD));
        const float4* V4 = (const float4*)(sP + 2 * (NH * SS * HD) + h * (SS * HD));
        // no-max softmax: scores are O(+-12), exp() safe in fp32; softmax is
        // shift-invariant so this matches jax.nn.softmax within threshold.
        for (int k = 0; k < SS; ++k) {
            const float4 kv = K4[k];
            const float sc = q0 * kv.x + q1 * kv.y + q2 * kv.z + q3 * kv.w;
            const float pterm = __expf(sc);
            const float4 vv = V4[k];
            l += pterm;
            acc0 += pterm * vv.x;
            acc1 += pterm * vv.y;
            acc2 += pterm * vv.z;
            acc3 += pterm * vv.w;
        }
    }
    __syncthreads();   // everyone past sP reads before sRaw reuse below? (no
                       // alias: comb writes go to sRaw which is idle; this sync
                       // orders comb writes vs the final-projection reads)
    if (t < 204) {
        const float inv = 1.f / l;
        float* comb = sRaw + qr * HID + h * HD;   // recombine heads
        comb[0] = acc0 * inv;
        comb[1] = acc1 * inv;
        comb[2] = acc2 * inv;
        comb[3] = acc3 * inv;
    }
    __syncthreads();

    // ---- output projection (wo) + coalesced store ----
    for (int e = t; e < 816; e += 256) {
        const int s = e >> 3, i = e & 7;
        const float* comb = sRaw + s * HID;
        const float* w    = sW + 3 * 64 + i * 8;
        float x = 0.f;
#pragma unroll
        for (int j = 0; j < 8; ++j) x += comb[j] * w[j];
        out[(size_t)b * (SS * HID) + e] = x;
    }
}

extern "C" void kernel_launch(void* const* d_in, const int* in_sizes, int n_in,
                              void* d_out, int out_size, void* d_ws, size_t ws_size,
                              hipStream_t stream) {
    const float* query = (const float*)d_in[0];
    const float* key   = (const float*)d_in[1];
    const float* value = (const float*)d_in[2];
    const float* wq    = (const float*)d_in[3];
    const float* wk    = (const float*)d_in[4];
    const float* wv    = (const float*)d_in[5];
    const float* wo    = (const float*)d_in[6];
    float* out = (float*)d_out;
    mha_fused_kernel<<<NB, 256, 0, stream>>>(query, key, value, wq, wk, wv, wo, out);
}